// Round 1
// baseline (1532.201 us; speedup 1.0000x reference)
//
#include <hip/hip_runtime.h>
#include <hip/hip_bf16.h>

// GCN fused pipeline for MI355X.
// Inputs (fp32 unless noted):
//  0 x[int32 N] (all 0, vocab=1), 1 edge_index[int32 2*E] (src=first E, dst=next E),
//  2 batch[int32 N] (sorted), 3 emb[1*64], 4 W1[64*64], 5 b1[64],
//  6 W2[64*64], 7 b2[64], 8 fcW[64*32], 9 fcb[32].
// Output: [G=64, 32] fp32.

#define DH 64
#define DOUT 32

// ---- edge kernels ----
__global__ void k_deg(const int* __restrict__ dst, float* __restrict__ degf, int E) {
    int e = blockIdx.x * blockDim.x + threadIdx.x;
    if (e < E) atomicAdd(&degf[dst[e]], 1.0f);
}

__global__ void k_dinv(const float* __restrict__ degf, float* __restrict__ dinv, int N) {
    int i = blockIdx.x * blockDim.x + threadIdx.x;
    if (i < N) dinv[i] = 1.0f / sqrtf(degf[i] + 1.0f);
}

__global__ void k_S(const int* __restrict__ src, const int* __restrict__ dst,
                    const float* __restrict__ dinv, float* __restrict__ S, int E) {
    int e = blockIdx.x * blockDim.x + threadIdx.x;
    if (e < E) atomicAdd(&S[dst[e]], dinv[src[e]]);
}

// ---- tiny: embW1[d] = sum_k emb[k] * W1[k][d]  (vocab = 1) ----
__global__ void k_embw1(const float* __restrict__ emb, const float* __restrict__ W1,
                        float* __restrict__ embW1) {
    int d = threadIdx.x;  // 64 threads
    float s = 0.f;
#pragma unroll
    for (int k = 0; k < DH; ++k) s += emb[k] * W1[k * DH + d];
    embW1[d] = s;
}

// ---- h1[i][d] = relu(embW1[d] * dinv_i*(S_i+dinv_i) + b1[d]) ----
__global__ void k_h1(const float* __restrict__ dinv, const float* __restrict__ S,
                     const float* __restrict__ embW1, const float* __restrict__ b1,
                     float* __restrict__ h1, int N) {
    int idx = blockIdx.x * blockDim.x + threadIdx.x;
    if (idx >= N * DH) return;
    int i = idx >> 6, d = idx & 63;
    float di = dinv[i];
    float c = di * (S[i] + di);
    h1[idx] = fmaxf(embW1[d] * c + b1[d], 0.0f);
}

// ---- g[i][d] = dinv_i * sum_k h1[i][k] * W2[k][d] ----
__global__ void k_mm_g(const float* __restrict__ h1, const float* __restrict__ W2,
                       const float* __restrict__ dinv, float* __restrict__ g, int N) {
    __shared__ float Ws[DH * DH];
    for (int t = threadIdx.x; t < DH * DH; t += blockDim.x) Ws[t] = W2[t];
    __syncthreads();
    int idx = blockIdx.x * blockDim.x + threadIdx.x;
    if (idx >= N * DH) return;
    int i = idx >> 6, d = idx & 63;
    const float* row = h1 + (size_t)i * DH;
    float s = 0.f;
#pragma unroll
    for (int k = 0; k < DH; ++k) s += row[k] * Ws[k * DH + d];
    g[idx] = dinv[i] * s;
}

// ---- acc[dst[e]][d] += g[src[e]][d]; one wave handles one edge's 64 dims ----
__global__ void k_scatter(const int* __restrict__ src, const int* __restrict__ dst,
                          const float* __restrict__ g, float* __restrict__ acc, int E) {
    int idx = blockIdx.x * blockDim.x + threadIdx.x;
    if (idx >= E * DH) return;
    int e = idx >> 6, d = idx & 63;
    int s = src[e], t = dst[e];
    atomicAdd(&acc[(size_t)t * DH + d], g[(size_t)s * DH + d]);
}

// ---- h2 = relu(dinv*(acc+g) + b2); pool atomics ----
__global__ void k_h2pool(const float* __restrict__ acc, const float* __restrict__ g,
                         const float* __restrict__ dinv, const float* __restrict__ b2,
                         const int* __restrict__ batch, float* __restrict__ psum,
                         float* __restrict__ cnt, int N) {
    int idx = blockIdx.x * blockDim.x + threadIdx.x;
    if (idx >= N * DH) return;
    int i = idx >> 6, d = idx & 63;
    float v = fmaxf(dinv[i] * (acc[idx] + g[idx]) + b2[d], 0.0f);
    int b = batch[i];
    atomicAdd(&psum[b * DH + d], v);
    if (d == 0) atomicAdd(&cnt[b], 1.0f);
}

// ---- out[g][o] = (psum[g]/max(cnt,1)) . fcW[:,o] + fcb[o] ----
__global__ void k_out(const float* __restrict__ psum, const float* __restrict__ cnt,
                      const float* __restrict__ fcW, const float* __restrict__ fcb,
                      float* __restrict__ out, int G) {
    int idx = blockIdx.x * blockDim.x + threadIdx.x;
    if (idx >= G * DOUT) return;
    int gi = idx >> 5, o = idx & 31;
    float c = fmaxf(cnt[gi], 1.0f);
    float s = 0.f;
#pragma unroll
    for (int d = 0; d < DH; ++d) s += psum[gi * DH + d] * fcW[d * DOUT + o];
    out[idx] = s / c + fcb[o];
}

extern "C" void kernel_launch(void* const* d_in, const int* in_sizes, int n_in,
                              void* d_out, int out_size, void* d_ws, size_t ws_size,
                              hipStream_t stream) {
    const int N = in_sizes[0];
    const int E = in_sizes[1] / 2;
    const int G = out_size / DOUT;

    const int* edge = (const int*)d_in[1];
    const int* src = edge;
    const int* dst = edge + E;
    const int* batch = (const int*)d_in[2];
    const float* emb = (const float*)d_in[3];
    const float* W1 = (const float*)d_in[4];
    const float* b1 = (const float*)d_in[5];
    const float* W2 = (const float*)d_in[6];
    const float* b2 = (const float*)d_in[7];
    const float* fcW = (const float*)d_in[8];
    const float* fcb = (const float*)d_in[9];
    float* out = (float*)d_out;

    // workspace layout (floats). Zero-init region first, then non-zeroed.
    float* ws = (float*)d_ws;
    float* degf  = ws;                    // N
    float* S     = degf + N;              // N
    float* acc   = S + N;                 // N*64
    float* psum  = acc + (size_t)N * DH;  // G*64
    float* cnt   = psum + (size_t)G * DH; // G
    size_t zero_floats = (size_t)2 * N + (size_t)N * DH + (size_t)G * DH + G;
    float* dinv  = cnt + G;               // N
    float* embW1 = dinv + N;              // 64
    float* h1    = embW1 + DH;            // N*64
    float* g     = h1 + (size_t)N * DH;   // N*64
    // total ~ 19.5M floats = 78 MB

    hipMemsetAsync(d_ws, 0, zero_floats * sizeof(float), stream);

    const int B = 256;
    k_deg<<<(E + B - 1) / B, B, 0, stream>>>(dst, degf, E);
    k_dinv<<<(N + B - 1) / B, B, 0, stream>>>(degf, dinv, N);
    k_S<<<(E + B - 1) / B, B, 0, stream>>>(src, dst, dinv, S, E);
    k_embw1<<<1, DH, 0, stream>>>(emb, W1, embW1);
    k_h1<<<(N * DH + B - 1) / B, B, 0, stream>>>(dinv, S, embW1, b1, h1, N);
    k_mm_g<<<(N * DH + B - 1) / B, B, 0, stream>>>(h1, W2, dinv, g, N);
    k_scatter<<<((size_t)E * DH + B - 1) / B, B, 0, stream>>>(src, dst, g, acc, E);
    k_h2pool<<<(N * DH + B - 1) / B, B, 0, stream>>>(acc, g, dinv, b2, batch, psum, cnt, N);
    k_out<<<(G * DOUT + B - 1) / B, B, 0, stream>>>(psum, cnt, fcW, fcb, out, G);
}

// Round 2
// 724.051 us; speedup vs baseline: 2.1162x; 2.1162x over previous
//
#include <hip/hip_runtime.h>
#include <hip/hip_bf16.h>

// GCN fused pipeline for MI355X.
// Inputs (fp32 unless noted):
//  0 x[int32 N] (all 0, vocab=1), 1 edge_index[int32 2*E] (src=first E, dst=next E),
//  2 batch[int32 N] (sorted), 3 emb[1*64], 4 W1[64*64], 5 b1[64],
//  6 W2[64*64], 7 b2[64], 8 fcW[64*32], 9 fcb[32].
// Output: [G=64, 32] fp32.

#define DH 64
#define DOUT 32

// ---- edge kernels ----
__global__ void k_deg(const int* __restrict__ dst, float* __restrict__ degf, int E) {
    int e = blockIdx.x * blockDim.x + threadIdx.x;
    if (e < E) atomicAdd(&degf[dst[e]], 1.0f);
}

__global__ void k_dinv(const float* __restrict__ degf, float* __restrict__ dinv, int N) {
    int i = blockIdx.x * blockDim.x + threadIdx.x;
    if (i < N) dinv[i] = 1.0f / sqrtf(degf[i] + 1.0f);
}

__global__ void k_S(const int* __restrict__ src, const int* __restrict__ dst,
                    const float* __restrict__ dinv, float* __restrict__ S, int E) {
    int e = blockIdx.x * blockDim.x + threadIdx.x;
    if (e < E) atomicAdd(&S[dst[e]], dinv[src[e]]);
}

// ---- tiny: embW1[d] = sum_k emb[k] * W1[k][d]  (vocab = 1) ----
__global__ void k_embw1(const float* __restrict__ emb, const float* __restrict__ W1,
                        float* __restrict__ embW1) {
    int d = threadIdx.x;  // 64 threads
    float s = 0.f;
#pragma unroll
    for (int k = 0; k < DH; ++k) s += emb[k] * W1[k * DH + d];
    embW1[d] = s;
}

// ---- h1[i][d] = relu(embW1[d] * dinv_i*(S_i+dinv_i) + b1[d]) ----
__global__ void k_h1(const float* __restrict__ dinv, const float* __restrict__ S,
                     const float* __restrict__ embW1, const float* __restrict__ b1,
                     float* __restrict__ h1, int N) {
    int idx = blockIdx.x * blockDim.x + threadIdx.x;
    if (idx >= N * DH) return;
    int i = idx >> 6, d = idx & 63;
    float di = dinv[i];
    float c = di * (S[i] + di);
    h1[idx] = fmaxf(embW1[d] * c + b1[d], 0.0f);
}

// ---- g[i][d] = dinv_i * sum_k h1[i][k] * W2[k][d] ----
__global__ void k_mm_g(const float* __restrict__ h1, const float* __restrict__ W2,
                       const float* __restrict__ dinv, float* __restrict__ g, int N) {
    __shared__ float Ws[DH * DH];
    for (int t = threadIdx.x; t < DH * DH; t += blockDim.x) Ws[t] = W2[t];
    __syncthreads();
    int idx = blockIdx.x * blockDim.x + threadIdx.x;
    if (idx >= N * DH) return;
    int i = idx >> 6, d = idx & 63;
    const float* row = h1 + (size_t)i * DH;
    float s = 0.f;
#pragma unroll
    for (int k = 0; k < DH; ++k) s += row[k] * Ws[k * DH + d];
    g[idx] = dinv[i] * s;
}

// ---- acc[dst[e]][d] += g[src[e]][d]; one wave handles one edge's 64 dims ----
__global__ void k_scatter(const int* __restrict__ src, const int* __restrict__ dst,
                          const float* __restrict__ g, float* __restrict__ acc, int E) {
    int idx = blockIdx.x * blockDim.x + threadIdx.x;
    if (idx >= E * DH) return;
    int e = idx >> 6, d = idx & 63;
    int s = src[e], t = dst[e];
    atomicAdd(&acc[(size_t)t * DH + d], g[(size_t)s * DH + d]);
}

// ---- h2 = relu(dinv*(acc+g) + b2); strip-mined pool using sorted batch ----
// Each block owns a contiguous node range [start, end). Thread (lane,d)
// accumulates privately; flush to psum only at batch-id boundaries.
__global__ void k_h2pool(const float* __restrict__ acc, const float* __restrict__ g,
                         const float* __restrict__ dinv, const float* __restrict__ b2,
                         const int* __restrict__ batch, float* __restrict__ psum,
                         float* __restrict__ cnt, int N, int chunk) {
    int d = threadIdx.x & 63;
    int lane = threadIdx.x >> 6;  // 0..3
    int start = blockIdx.x * chunk;
    int end = min(start + chunk, N);
    float bias = b2[d];
    float lsum = 0.f, lcnt = 0.f;
    int cb = -1;
    for (int i = start + lane; i < end; i += 4) {
        int b = batch[i];
        size_t idx = (size_t)i * DH + d;
        float v = fmaxf(dinv[i] * (acc[idx] + g[idx]) + bias, 0.0f);
        if (b != cb) {
            if (cb >= 0) {
                atomicAdd(&psum[cb * DH + d], lsum);
                if (d == 0) atomicAdd(&cnt[cb], lcnt);
            }
            cb = b; lsum = 0.f; lcnt = 0.f;
        }
        lsum += v;
        if (d == 0) lcnt += 1.f;
    }
    if (cb >= 0) {
        atomicAdd(&psum[cb * DH + d], lsum);
        if (d == 0) atomicAdd(&cnt[cb], lcnt);
    }
}

// ---- out[g][o] = (psum[g]/max(cnt,1)) . fcW[:,o] + fcb[o] ----
__global__ void k_out(const float* __restrict__ psum, const float* __restrict__ cnt,
                      const float* __restrict__ fcW, const float* __restrict__ fcb,
                      float* __restrict__ out, int G) {
    int idx = blockIdx.x * blockDim.x + threadIdx.x;
    if (idx >= G * DOUT) return;
    int gi = idx >> 5, o = idx & 31;
    float c = fmaxf(cnt[gi], 1.0f);
    float s = 0.f;
#pragma unroll
    for (int d = 0; d < DH; ++d) s += psum[gi * DH + d] * fcW[d * DOUT + o];
    out[idx] = s / c + fcb[o];
}

extern "C" void kernel_launch(void* const* d_in, const int* in_sizes, int n_in,
                              void* d_out, int out_size, void* d_ws, size_t ws_size,
                              hipStream_t stream) {
    const int N = in_sizes[0];
    const int E = in_sizes[1] / 2;
    const int G = out_size / DOUT;

    const int* edge = (const int*)d_in[1];
    const int* src = edge;
    const int* dst = edge + E;
    const int* batch = (const int*)d_in[2];
    const float* emb = (const float*)d_in[3];
    const float* W1 = (const float*)d_in[4];
    const float* b1 = (const float*)d_in[5];
    const float* W2 = (const float*)d_in[6];
    const float* b2 = (const float*)d_in[7];
    const float* fcW = (const float*)d_in[8];
    const float* fcb = (const float*)d_in[9];
    float* out = (float*)d_out;

    // workspace layout (floats). Zero-init region first, then non-zeroed.
    float* ws = (float*)d_ws;
    float* degf  = ws;                    // N
    float* S     = degf + N;              // N
    float* acc   = S + N;                 // N*64
    float* psum  = acc + (size_t)N * DH;  // G*64
    float* cnt   = psum + (size_t)G * DH; // G
    size_t zero_floats = (size_t)2 * N + (size_t)N * DH + (size_t)G * DH + G;
    float* dinv  = cnt + G;               // N
    float* embW1 = dinv + N;              // 64
    float* h1    = embW1 + DH;            // N*64
    float* g     = h1 + (size_t)N * DH;   // N*64
    // total ~ 19.5M floats = 78 MB

    hipMemsetAsync(d_ws, 0, zero_floats * sizeof(float), stream);

    const int B = 256;
    k_deg<<<(E + B - 1) / B, B, 0, stream>>>(dst, degf, E);
    k_dinv<<<(N + B - 1) / B, B, 0, stream>>>(degf, dinv, N);
    k_S<<<(E + B - 1) / B, B, 0, stream>>>(src, dst, dinv, S, E);
    k_embw1<<<1, DH, 0, stream>>>(emb, W1, embW1);
    k_h1<<<(N * DH + B - 1) / B, B, 0, stream>>>(dinv, S, embW1, b1, h1, N);
    k_mm_g<<<(N * DH + B - 1) / B, B, 0, stream>>>(h1, W2, dinv, g, N);
    k_scatter<<<((size_t)E * DH + B - 1) / B, B, 0, stream>>>(src, dst, g, acc, E);
    const int POOL_BLOCKS = 512;
    int chunk = (N + POOL_BLOCKS - 1) / POOL_BLOCKS;
    k_h2pool<<<POOL_BLOCKS, B, 0, stream>>>(acc, g, dinv, b2, batch, psum, cnt, N, chunk);
    k_out<<<(G * DOUT + B - 1) / B, B, 0, stream>>>(psum, cnt, fcW, fcb, out, G);
}

// Round 3
// 555.236 us; speedup vs baseline: 2.7596x; 1.3040x over previous
//
#include <hip/hip_runtime.h>
#include <hip/hip_bf16.h>

// GCN fused pipeline for MI355X — CSR-gather version (no fp32 atomic scatter).
// Inputs: 0 x[int32 N], 1 edge_index[int32 2*E] (src then dst), 2 batch[int32 N sorted],
// 3 emb[1*64], 4 W1[64*64], 5 b1[64], 6 W2[64*64], 7 b2[64], 8 fcW[64*32], 9 fcb[32].
// Output: [G=64, 32] fp32.

#define DH 64
#define DOUT 32
#define SCAN_B 256

// ---- deg counts (int atomics over 100K addrs — cheap) ----
__global__ void k_count(const int* __restrict__ dst, int* __restrict__ counts, int E) {
    int e = blockIdx.x * blockDim.x + threadIdx.x;
    if (e < E) atomicAdd(&counts[dst[e]], 1);
}

__global__ void k_dinv(const int* __restrict__ counts, float* __restrict__ dinv, int N) {
    int i = blockIdx.x * blockDim.x + threadIdx.x;
    if (i < N) dinv[i] = rsqrtf((float)counts[i] + 1.0f);
}

__global__ void k_S(const int* __restrict__ src, const int* __restrict__ dst,
                    const float* __restrict__ dinv, float* __restrict__ S, int E) {
    int e = blockIdx.x * blockDim.x + threadIdx.x;
    if (e < E) atomicAdd(&S[dst[e]], dinv[src[e]]);
}

// ---- embW1[d] = emb . W1[:,d] (vocab = 1) ----
__global__ void k_embw1(const float* __restrict__ emb, const float* __restrict__ W1,
                        float* __restrict__ embW1) {
    int d = threadIdx.x;
    float s = 0.f;
#pragma unroll
    for (int k = 0; k < DH; ++k) s += emb[k] * W1[k * DH + d];
    embW1[d] = s;
}

// ---- g[i][d] = dinv_i * sum_k relu(embW1[k]*c_i + b1[k]) * W2[k][d],
//      c_i = dinv_i*(S_i + dinv_i).  (h1 folded in; depends on i only via c_i) ----
__global__ void k_g(const float* __restrict__ dinv, const float* __restrict__ S,
                    const float* __restrict__ embW1, const float* __restrict__ b1,
                    const float* __restrict__ W2, float* __restrict__ g, int N) {
    __shared__ float Ws[DH * DH];
    __shared__ float ew[DH], bb[DH];
    for (int t = threadIdx.x; t < DH * DH; t += blockDim.x) Ws[t] = W2[t];
    if (threadIdx.x < DH) { ew[threadIdx.x] = embW1[threadIdx.x]; bb[threadIdx.x] = b1[threadIdx.x]; }
    __syncthreads();
    int idx = blockIdx.x * blockDim.x + threadIdx.x;
    if (idx >= N * DH) return;
    int i = idx >> 6, d = idx & 63;
    float di = dinv[i];
    float c = di * (S[i] + di);
    float s = 0.f;
#pragma unroll
    for (int k = 0; k < DH; ++k) {
        float a = fmaxf(ew[k] * c + bb[k], 0.0f);
        s += a * Ws[k * DH + d];
    }
    g[idx] = di * s;
}

// ---- CSR build: block scan -> block-sum scan -> add-back; then cursor fill ----
__global__ void k_scan1(const int* __restrict__ counts, int* __restrict__ rowptr,
                        int* __restrict__ bsums, int N) {
    __shared__ int tmp[SCAN_B];
    int i = blockIdx.x * SCAN_B + threadIdx.x;
    int v = (i < N) ? counts[i] : 0;
    tmp[threadIdx.x] = v;
    __syncthreads();
    for (int off = 1; off < SCAN_B; off <<= 1) {
        int t = (threadIdx.x >= off) ? tmp[threadIdx.x - off] : 0;
        __syncthreads();
        tmp[threadIdx.x] += t;
        __syncthreads();
    }
    if (i < N) rowptr[i] = tmp[threadIdx.x] - v;  // exclusive within block
    if (threadIdx.x == SCAN_B - 1) bsums[blockIdx.x] = tmp[SCAN_B - 1];
}

__global__ void k_scan2(int* __restrict__ bsums, int nb) {
    __shared__ int tmp[512];
    int t = threadIdx.x;
    int v = (t < nb) ? bsums[t] : 0;
    tmp[t] = v;
    __syncthreads();
    for (int off = 1; off < 512; off <<= 1) {
        int u = (t >= off) ? tmp[t - off] : 0;
        __syncthreads();
        tmp[t] += u;
        __syncthreads();
    }
    if (t < nb) bsums[t] = tmp[t] - v;  // exclusive
}

__global__ void k_scan3(int* __restrict__ rowptr, const int* __restrict__ bsums,
                        int* __restrict__ cursor, int N, int E) {
    int i = blockIdx.x * blockDim.x + threadIdx.x;
    if (i < N) {
        int v = rowptr[i] + bsums[i / SCAN_B];
        rowptr[i] = v;
        cursor[i] = v;
    }
    if (i == 0) rowptr[N] = E;
}

__global__ void k_fill(const int* __restrict__ src, const int* __restrict__ dst,
                       int* __restrict__ cursor, int* __restrict__ esrc, int E) {
    int e = blockIdx.x * blockDim.x + threadIdx.x;
    if (e < E) {
        int p = atomicAdd(&cursor[dst[e]], 1);
        esrc[p] = src[e];
    }
}

// ---- fused: per-node gather of g rows + h2 relu + sorted-batch strip pooling.
// One wave per node (lane = dim). Edge sources loaded lane-parallel, broadcast
// via __shfl. Pool flushes to psum only at batch-id boundaries. ----
__global__ void k_gather_pool(const int* __restrict__ rowptr, const int* __restrict__ esrc,
                              const float* __restrict__ g, const float* __restrict__ dinv,
                              const float* __restrict__ b2, const int* __restrict__ batch,
                              float* __restrict__ psum, float* __restrict__ cnt,
                              int N, int chunk) {
    int d = threadIdx.x & 63;
    int w = threadIdx.x >> 6;  // wave in block: 0..3
    int start = blockIdx.x * chunk;
    int end = min(start + chunk, N);
    float bias = b2[d];
    float lsum = 0.f, lcnt = 0.f;
    int cb = -1;
    for (int i = start + w; i < end; i += 4) {
        int r0 = rowptr[i], r1 = rowptr[i + 1];
        float agg = 0.f;
        for (int base = r0; base < r1; base += 64) {
            int nb = min(64, r1 - base);
            int s_l = (d < nb) ? esrc[base + d] : 0;
            for (int j = 0; j < nb; ++j) {
                int s = __shfl(s_l, j);
                agg += g[(size_t)s * DH + d];
            }
        }
        float v = fmaxf(dinv[i] * (agg + g[(size_t)i * DH + d]) + bias, 0.0f);
        int b = batch[i];
        if (b != cb) {
            if (cb >= 0) {
                atomicAdd(&psum[cb * DH + d], lsum);
                if (d == 0) atomicAdd(&cnt[cb], lcnt);
            }
            cb = b; lsum = 0.f; lcnt = 0.f;
        }
        lsum += v;
        if (d == 0) lcnt += 1.f;
    }
    if (cb >= 0) {
        atomicAdd(&psum[cb * DH + d], lsum);
        if (d == 0) atomicAdd(&cnt[cb], lcnt);
    }
}

// ---- out[g][o] = (psum[g]/max(cnt,1)) . fcW[:,o] + fcb[o] ----
__global__ void k_out(const float* __restrict__ psum, const float* __restrict__ cnt,
                      const float* __restrict__ fcW, const float* __restrict__ fcb,
                      float* __restrict__ out, int G) {
    int idx = blockIdx.x * blockDim.x + threadIdx.x;
    if (idx >= G * DOUT) return;
    int gi = idx >> 5, o = idx & 31;
    float c = fmaxf(cnt[gi], 1.0f);
    float s = 0.f;
#pragma unroll
    for (int d = 0; d < DH; ++d) s += psum[gi * DH + d] * fcW[d * DOUT + o];
    out[idx] = s / c + fcb[o];
}

static inline size_t pad256(size_t n) { return (n + 255) & ~(size_t)255; }

extern "C" void kernel_launch(void* const* d_in, const int* in_sizes, int n_in,
                              void* d_out, int out_size, void* d_ws, size_t ws_size,
                              hipStream_t stream) {
    const int N = in_sizes[0];
    const int E = in_sizes[1] / 2;
    const int G = out_size / DOUT;

    const int* edge = (const int*)d_in[1];
    const int* src = edge;
    const int* dst = edge + E;
    const int* batch = (const int*)d_in[2];
    const float* emb = (const float*)d_in[3];
    const float* W1 = (const float*)d_in[4];
    const float* b1 = (const float*)d_in[5];
    const float* W2 = (const float*)d_in[6];
    const float* b2 = (const float*)d_in[7];
    const float* fcW = (const float*)d_in[8];
    const float* fcb = (const float*)d_in[9];
    float* out = (float*)d_out;

    // workspace layout (4-byte elements, 256-elt padded for alignment).
    // Zeroed region first: counts, S, psum, cnt.
    char* ws = (char*)d_ws;
    size_t off = 0;
    int* counts = (int*)(ws + off);   off += pad256(N) * 4;
    float* S    = (float*)(ws + off); off += pad256(N) * 4;
    float* psum = (float*)(ws + off); off += pad256((size_t)G * DH) * 4;
    float* cnt  = (float*)(ws + off); off += pad256(G) * 4;
    size_t zero_bytes = off;
    float* dinv  = (float*)(ws + off); off += pad256(N) * 4;
    float* embW1 = (float*)(ws + off); off += pad256(DH) * 4;
    float* g     = (float*)(ws + off); off += pad256((size_t)N * DH) * 4;
    int* rowptr  = (int*)(ws + off);   off += pad256(N + 1) * 4;
    int* cursor  = (int*)(ws + off);   off += pad256(N) * 4;
    int* bsums   = (int*)(ws + off);   off += pad256((N + SCAN_B - 1) / SCAN_B) * 4;
    int* esrc    = (int*)(ws + off);   off += pad256(E) * 4;
    // total ~ 34 MB

    hipMemsetAsync(d_ws, 0, zero_bytes, stream);

    const int B = 256;
    const int nb = (N + SCAN_B - 1) / SCAN_B;
    k_count<<<(E + B - 1) / B, B, 0, stream>>>(dst, counts, E);
    k_dinv<<<(N + B - 1) / B, B, 0, stream>>>(counts, dinv, N);
    k_S<<<(E + B - 1) / B, B, 0, stream>>>(src, dst, dinv, S, E);
    k_embw1<<<1, DH, 0, stream>>>(emb, W1, embW1);
    k_g<<<(N * DH + B - 1) / B, B, 0, stream>>>(dinv, S, embW1, b1, W2, g, N);
    k_scan1<<<nb, SCAN_B, 0, stream>>>(counts, rowptr, bsums, N);
    k_scan2<<<1, 512, 0, stream>>>(bsums, nb);
    k_scan3<<<(N + B - 1) / B, B, 0, stream>>>(rowptr, bsums, cursor, N, E);
    k_fill<<<(E + B - 1) / B, B, 0, stream>>>(src, dst, cursor, esrc, E);
    const int GP_BLOCKS = 2048;
    int chunk = (N + GP_BLOCKS - 1) / GP_BLOCKS;
    k_gather_pool<<<GP_BLOCKS, B, 0, stream>>>(rowptr, esrc, g, dinv, b2, batch,
                                               psum, cnt, N, chunk);
    k_out<<<(G * DOUT + B - 1) / B, B, 0, stream>>>(psum, cnt, fcW, fcb, out, G);
}

// Round 4
// 426.553 us; speedup vs baseline: 3.5921x; 1.3017x over previous
//
#include <hip/hip_runtime.h>
#include <hip/hip_bf16.h>

// GCN fused pipeline for MI355X — hinge-table rank-1 version.
// Key fact: vocab=1 => every node's layer-1 input row is identical, so
// h1[i] = relu(embW1 * c_i + b1) is piecewise-linear in the scalar
// c_i = dinv_i*(S_i+dinv_i). With 65 prefix tables P/Q over ReLU active sets,
// g[i][d] = a_i*P[bin_i][d] + b_i*Q[bin_i][d], a_i = dinv_i*c_i, b_i = dinv_i.
// The edge aggregation then needs only 9 bytes per source node.
// Inputs: 0 x[int32 N], 1 edge_index[int32 2*E] (src then dst), 2 batch[int32 N sorted],
// 3 emb[1*64], 4 W1[64*64], 5 b1[64], 6 W2[64*64], 7 b2[64], 8 fcW[64*32], 9 fcb[32].
// Output: [G=64, 32] fp32.

#define DH 64
#define DOUT 32
#define NBIN 65
#define SCAN_B 256

__global__ void k_count(const int* __restrict__ dst, int* __restrict__ counts, int E) {
    int e = blockIdx.x * blockDim.x + threadIdx.x;
    if (e < E) atomicAdd(&counts[dst[e]], 1);
}

__global__ void k_dinv(const int* __restrict__ counts, float* __restrict__ dinv, int N) {
    int i = blockIdx.x * blockDim.x + threadIdx.x;
    if (i < N) dinv[i] = rsqrtf((float)counts[i] + 1.0f);
}

// ---- CSR build: block scan -> block-sum scan -> add-back; then cursor fill ----
__global__ void k_scan1(const int* __restrict__ counts, int* __restrict__ rowptr,
                        int* __restrict__ bsums, int N) {
    __shared__ int tmp[SCAN_B];
    int i = blockIdx.x * SCAN_B + threadIdx.x;
    int v = (i < N) ? counts[i] : 0;
    tmp[threadIdx.x] = v;
    __syncthreads();
    for (int off = 1; off < SCAN_B; off <<= 1) {
        int t = (threadIdx.x >= off) ? tmp[threadIdx.x - off] : 0;
        __syncthreads();
        tmp[threadIdx.x] += t;
        __syncthreads();
    }
    if (i < N) rowptr[i] = tmp[threadIdx.x] - v;  // exclusive within block
    if (threadIdx.x == SCAN_B - 1) bsums[blockIdx.x] = tmp[SCAN_B - 1];
}

__global__ void k_scan2(int* __restrict__ bsums, int nb) {
    __shared__ int tmp[512];
    int t = threadIdx.x;
    int v = (t < nb) ? bsums[t] : 0;
    tmp[t] = v;
    __syncthreads();
    for (int off = 1; off < 512; off <<= 1) {
        int u = (t >= off) ? tmp[t - off] : 0;
        __syncthreads();
        tmp[t] += u;
        __syncthreads();
    }
    if (t < nb) bsums[t] = tmp[t] - v;  // exclusive
}

__global__ void k_scan3(int* __restrict__ rowptr, const int* __restrict__ bsums,
                        int* __restrict__ cursor, int N, int E) {
    int i = blockIdx.x * blockDim.x + threadIdx.x;
    if (i < N) {
        int v = rowptr[i] + bsums[i / SCAN_B];
        rowptr[i] = v;
        cursor[i] = v;
    }
    if (i == 0) rowptr[N] = E;
}

__global__ void k_fill(const int* __restrict__ src, const int* __restrict__ dst,
                       int* __restrict__ cursor, int* __restrict__ esrc, int E) {
    int e = blockIdx.x * blockDim.x + threadIdx.x;
    if (e < E) {
        int p = atomicAdd(&cursor[dst[e]], 1);
        esrc[p] = src[e];
    }
}

// ---- embW1, hinge breakpoints t_k, ranks r_k = #{t<=t_k}, s_k = #{t<t_k} ----
__global__ void k_prep(const float* __restrict__ emb, const float* __restrict__ W1,
                       const float* __restrict__ b1, float* __restrict__ ew,
                       float* __restrict__ tarr, int* __restrict__ rarr,
                       int* __restrict__ sarr) {
    __shared__ float tl[DH];
    int k = threadIdx.x;  // 64 threads
    float s = 0.f;
#pragma unroll
    for (int j = 0; j < DH; ++j) s += emb[j] * W1[j * DH + k];
    float t = (s != 0.f) ? (-b1[k] / s) : INFINITY;
    tl[k] = t;
    ew[k] = s;
    tarr[k] = t;
    __syncthreads();
    int r = 0, ss = 0;
#pragma unroll
    for (int j = 0; j < DH; ++j) { r += (tl[j] <= t); ss += (tl[j] < t); }
    rarr[k] = r;
    sarr[k] = ss;
}

// ---- P[beta][d] = sum_{k active in bin beta} ew[k]*W2[k][d]; Q same with b1[k] ----
__global__ void k_tables(const float* __restrict__ ew, const float* __restrict__ b1,
                         const float* __restrict__ W2, const int* __restrict__ rarr,
                         const int* __restrict__ sarr, float* __restrict__ P,
                         float* __restrict__ Q) {
    int beta = blockIdx.x;   // 0..64
    int d = threadIdx.x;     // 0..63
    float p = 0.f, q = 0.f;
    for (int k = 0; k < DH; ++k) {
        float e = ew[k];
        bool act;
        if (e > 0.f) act = (beta >= rarr[k]);        // active iff c > t_k
        else if (e < 0.f) act = (beta <= sarr[k]);   // active iff c < t_k
        else act = (b1[k] > 0.f);                    // constant hinge
        if (act) {
            float w = W2[k * DH + d];
            p += e * w;
            q += b1[k] * w;
        }
    }
    P[beta * DH + d] = p;
    Q[beta * DH + d] = q;
}

// ---- per-node: S_i via CSR walk, c_i, (a_i,b_i), bin_i ----
__global__ void k_node(const int* __restrict__ rowptr, const int* __restrict__ esrc,
                       const float* __restrict__ dinv, const float* __restrict__ tarr,
                       float2* __restrict__ ab, unsigned char* __restrict__ bin, int N) {
    __shared__ float tl[DH];
    if (threadIdx.x < DH) tl[threadIdx.x] = tarr[threadIdx.x];
    __syncthreads();
    int i = blockIdx.x * blockDim.x + threadIdx.x;
    if (i >= N) return;
    int r0 = rowptr[i], r1 = rowptr[i + 1];
    float S = 0.f;
    for (int j = r0; j < r1; ++j) S += dinv[esrc[j]];
    float di = dinv[i];
    float c = di * (S + di);
    ab[i] = make_float2(di * c, di);
    int b = 0;
#pragma unroll
    for (int j = 0; j < DH; ++j) b += (tl[j] < c);
    bin[i] = (unsigned char)b;
}

// ---- fused gather + h2 relu + sorted-batch strip pooling.
// One wave per node (lane=dim). Per edge: 9B random read of source summary,
// broadcast via shfl, 2 LDS table reads + 2 FMAs per lane. ----
__global__ void k_gather_pool(const int* __restrict__ rowptr, const int* __restrict__ esrc,
                              const float2* __restrict__ ab, const unsigned char* __restrict__ bin,
                              const float* __restrict__ P, const float* __restrict__ Q,
                              const float* __restrict__ b2, const int* __restrict__ batch,
                              float* __restrict__ psum, float* __restrict__ cnt,
                              int N, int chunk) {
    __shared__ float Ps[NBIN * DH];
    __shared__ float Qs[NBIN * DH];
    for (int t = threadIdx.x; t < NBIN * DH; t += blockDim.x) { Ps[t] = P[t]; Qs[t] = Q[t]; }
    __syncthreads();
    int d = threadIdx.x & 63;
    int w = threadIdx.x >> 6;  // wave in block: 0..3
    int start = blockIdx.x * chunk;
    int end = min(start + chunk, N);
    float bias = b2[d];
    float lsum = 0.f, lcnt = 0.f;
    int cb = -1;
    for (int i = start + w; i < end; i += 4) {
        int r0 = rowptr[i], r1 = rowptr[i + 1];
        float agg = 0.f;
        for (int base = r0; base < r1; base += 64) {
            int nb = min(64, r1 - base);
            float2 abl = make_float2(0.f, 0.f);
            int bl = 0;
            if (d < nb) {
                int s = esrc[base + d];
                abl = ab[s];
                bl = bin[s];
            }
            for (int j = 0; j < nb; ++j) {
                float a = __shfl(abl.x, j);
                float b = __shfl(abl.y, j);
                int be = __shfl(bl, j);
                agg += a * Ps[be * DH + d] + b * Qs[be * DH + d];
            }
        }
        float2 me = ab[i];
        int mb = bin[i];
        float gi = me.x * Ps[mb * DH + d] + me.y * Qs[mb * DH + d];
        float v = fmaxf(me.y * (agg + gi) + bias, 0.0f);
        int b = batch[i];
        if (b != cb) {
            if (cb >= 0) {
                atomicAdd(&psum[cb * DH + d], lsum);
                if (d == 0) atomicAdd(&cnt[cb], lcnt);
            }
            cb = b; lsum = 0.f; lcnt = 0.f;
        }
        lsum += v;
        if (d == 0) lcnt += 1.f;
    }
    if (cb >= 0) {
        atomicAdd(&psum[cb * DH + d], lsum);
        if (d == 0) atomicAdd(&cnt[cb], lcnt);
    }
}

// ---- out[g][o] = (psum[g]/max(cnt,1)) . fcW[:,o] + fcb[o] ----
__global__ void k_out(const float* __restrict__ psum, const float* __restrict__ cnt,
                      const float* __restrict__ fcW, const float* __restrict__ fcb,
                      float* __restrict__ out, int G) {
    int idx = blockIdx.x * blockDim.x + threadIdx.x;
    if (idx >= G * DOUT) return;
    int gi = idx >> 5, o = idx & 31;
    float c = fmaxf(cnt[gi], 1.0f);
    float s = 0.f;
#pragma unroll
    for (int d = 0; d < DH; ++d) s += psum[gi * DH + d] * fcW[d * DOUT + o];
    out[idx] = s / c + fcb[o];
}

static inline size_t pad256(size_t n) { return (n + 255) & ~(size_t)255; }

extern "C" void kernel_launch(void* const* d_in, const int* in_sizes, int n_in,
                              void* d_out, int out_size, void* d_ws, size_t ws_size,
                              hipStream_t stream) {
    const int N = in_sizes[0];
    const int E = in_sizes[1] / 2;
    const int G = out_size / DOUT;

    const int* edge = (const int*)d_in[1];
    const int* src = edge;
    const int* dst = edge + E;
    const int* batch = (const int*)d_in[2];
    const float* emb = (const float*)d_in[3];
    const float* W1 = (const float*)d_in[4];
    const float* b1 = (const float*)d_in[5];
    const float* W2 = (const float*)d_in[6];
    const float* b2 = (const float*)d_in[7];
    const float* fcW = (const float*)d_in[8];
    const float* fcb = (const float*)d_in[9];
    float* out = (float*)d_out;

    // workspace layout. Zero region first: counts, psum, cnt.
    char* ws = (char*)d_ws;
    size_t off = 0;
    int* counts = (int*)(ws + off);    off += pad256(N) * 4;
    float* psum = (float*)(ws + off);  off += pad256((size_t)G * DH) * 4;
    float* cnt  = (float*)(ws + off);  off += pad256(G) * 4;
    size_t zero_bytes = off;
    float* dinv   = (float*)(ws + off); off += pad256(N) * 4;
    int* rowptr   = (int*)(ws + off);   off += pad256(N + 1) * 4;
    int* cursor   = (int*)(ws + off);   off += pad256(N) * 4;
    int* bsums    = (int*)(ws + off);   off += pad256((N + SCAN_B - 1) / SCAN_B) * 4;
    int* esrc     = (int*)(ws + off);   off += pad256(E) * 4;
    float* ew     = (float*)(ws + off); off += pad256(DH) * 4;
    float* tarr   = (float*)(ws + off); off += pad256(DH) * 4;
    int* rarr     = (int*)(ws + off);   off += pad256(DH) * 4;
    int* sarr     = (int*)(ws + off);   off += pad256(DH) * 4;
    float* Ptab   = (float*)(ws + off); off += pad256(NBIN * DH) * 4;
    float* Qtab   = (float*)(ws + off); off += pad256(NBIN * DH) * 4;
    float2* ab    = (float2*)(ws + off); off += pad256(N) * 8;
    unsigned char* bin = (unsigned char*)(ws + off); off += pad256(N);

    hipMemsetAsync(d_ws, 0, zero_bytes, stream);

    const int B = 256;
    const int nb = (N + SCAN_B - 1) / SCAN_B;
    k_count<<<(E + B - 1) / B, B, 0, stream>>>(dst, counts, E);
    k_dinv<<<(N + B - 1) / B, B, 0, stream>>>(counts, dinv, N);
    k_scan1<<<nb, SCAN_B, 0, stream>>>(counts, rowptr, bsums, N);
    k_scan2<<<1, 512, 0, stream>>>(bsums, nb);
    k_scan3<<<(N + B - 1) / B, B, 0, stream>>>(rowptr, bsums, cursor, N, E);
    k_fill<<<(E + B - 1) / B, B, 0, stream>>>(src, dst, cursor, esrc, E);
    k_prep<<<1, DH, 0, stream>>>(emb, W1, b1, ew, tarr, rarr, sarr);
    k_tables<<<NBIN, DH, 0, stream>>>(ew, b1, W2, rarr, sarr, Ptab, Qtab);
    k_node<<<(N + B - 1) / B, B, 0, stream>>>(rowptr, esrc, dinv, tarr, ab, bin, N);
    const int GP_BLOCKS = 2048;
    int chunk = (N + GP_BLOCKS - 1) / GP_BLOCKS;
    k_gather_pool<<<GP_BLOCKS, B, 0, stream>>>(rowptr, esrc, ab, bin, Ptab, Qtab,
                                               b2, batch, psum, cnt, N, chunk);
    k_out<<<(G * DOUT + B - 1) / B, B, 0, stream>>>(psum, cnt, fcW, fcb, out, G);
}